// Round 1
// baseline (674.352 us; speedup 1.0000x reference)
//
#include <hip/hip_runtime.h>

// FSMN depthwise strided FIR, parity-decomposed register-sliding implementation.
// B=32, T=2000, D=512, L_ORDER=R_ORDER=20, strides=2.
//
// out[b,2m  ,d] = sum_{i=0..20} fL[i]*xe[m-20+i] + sum_{j=0..19} fR[j]*xo[m+j]
// out[b,2m+1,d] = sum_{i=0..20} fL[i]*xo[m-20+i] + sum_{j=0..19} fR[j]*xe[m+1+j]
// where xe[s]=x[b,2s,d], xo[s]=x[b,2s+1,d], fL=filt[0..20], fR=filt[21..40].

#define B_ 32
#define T_ 2000
#define D_ 512
#define S_ 1000   // T/2 (downsampled length)
#define M_ 8      // m-positions per thread (=> 16 output rows per thread)

__device__ __forceinline__ float4 zf4() {
    float4 z; z.x = 0.f; z.y = 0.f; z.z = 0.f; z.w = 0.f; return z;
}

__device__ __forceinline__ void fma4(float4& a, const float4 f, const float4 w) {
    a.x = fmaf(f.x, w.x, a.x);
    a.y = fmaf(f.y, w.y, a.y);
    a.z = fmaf(f.z, w.z, a.z);
    a.w = fmaf(f.w, w.w, a.w);
}

__global__ __launch_bounds__(256, 2) void fsmn_kernel(
    const float* __restrict__ x, const float* __restrict__ filt,
    float* __restrict__ out)
{
    const int d4 = threadIdx.x;            // 0..63 : float4 index within d-half
    const int mg = threadIdx.y;            // 0..3  : m-group within block
    const int mb = blockIdx.x;             // 0..31 : m-block
    const int dh = blockIdx.y;             // 0..1  : d-half
    const int b  = blockIdx.z;             // 0..31 : batch

    const int m0 = (mb * 4 + mg) * M_;     // base m for this thread
    if (m0 >= S_) return;                  // tail blocks (125 groups, grid has 128)

    const int d = (dh * 64 + d4) * 4;
    const float* xb = x + (size_t)b * T_ * D_ + d;
    const float* fb = filt + d;
    float*       ob = out + (size_t)b * T_ * D_ + d;

    // Bounds-checked downsampled loads (zero padding outside [0,S_)).
    auto ldE = [&](int s) -> float4 {
        if ((unsigned)s < (unsigned)S_)
            return *(const float4*)(xb + (size_t)(2 * s) * D_);
        return zf4();
    };
    auto ldO = [&](int s) -> float4 {
        if ((unsigned)s < (unsigned)S_)
            return *(const float4*)(xb + (size_t)(2 * s + 1) * D_);
        return zf4();
    };

    float4 ae[M_], ao[M_];
#pragma unroll
    for (int m = 0; m < M_; ++m) { ae[m] = zf4(); ao[m] = zf4(); }

    float4 we[M_], wo[M_];

    // ---- Left passes (taps fL[0..20]) for both parities ----
    // even out uses xe[m0-20+i+m], odd out uses xo[m0-20+i+m]
#pragma unroll
    for (int m = 0; m < M_; ++m) {
        we[m] = ldE(m0 - 20 + m);
        wo[m] = ldO(m0 - 20 + m);
    }
#pragma unroll
    for (int i = 0; i < 21; ++i) {
        const float4 fv = *(const float4*)(fb + i * D_);
#pragma unroll
        for (int m = 0; m < M_; ++m) {
            fma4(ae[m], fv, we[m]);
            fma4(ao[m], fv, wo[m]);
        }
        if (i < 20) {
#pragma unroll
            for (int m = 0; m < M_ - 1; ++m) { we[m] = we[m + 1]; wo[m] = wo[m + 1]; }
            we[M_ - 1] = ldE(m0 - 20 + i + 1 + (M_ - 1));
            wo[M_ - 1] = ldO(m0 - 20 + i + 1 + (M_ - 1));
        }
    }

    // ---- Right passes (taps fR[0..19]) for both parities ----
    // even out uses xo[m0+j+m], odd out uses xe[m0+1+j+m]
#pragma unroll
    for (int m = 0; m < M_; ++m) {
        wo[m] = ldO(m0 + m);
        we[m] = ldE(m0 + 1 + m);
    }
#pragma unroll
    for (int j = 0; j < 20; ++j) {
        const float4 fv = *(const float4*)(fb + (21 + j) * D_);
#pragma unroll
        for (int m = 0; m < M_; ++m) {
            fma4(ae[m], fv, wo[m]);
            fma4(ao[m], fv, we[m]);
        }
        if (j < 19) {
#pragma unroll
            for (int m = 0; m < M_ - 1; ++m) { we[m] = we[m + 1]; wo[m] = wo[m + 1]; }
            wo[M_ - 1] = ldO(m0 + j + 1 + (M_ - 1));
            we[M_ - 1] = ldE(m0 + 1 + j + 1 + (M_ - 1));
        }
    }

    // ---- Store 2*M_ output rows (coalesced float4 across 64 lanes) ----
#pragma unroll
    for (int m = 0; m < M_; ++m) {
        *(float4*)(ob + (size_t)(2 * (m0 + m))     * D_) = ae[m];
        *(float4*)(ob + (size_t)(2 * (m0 + m) + 1) * D_) = ao[m];
    }
}

extern "C" void kernel_launch(void* const* d_in, const int* in_sizes, int n_in,
                              void* d_out, int out_size, void* d_ws, size_t ws_size,
                              hipStream_t stream) {
    const float* x    = (const float*)d_in[0];
    const float* filt = (const float*)d_in[1];
    float*       out  = (float*)d_out;

    dim3 block(64, 4, 1);
    // grid.x covers ceil(125 m-groups-of-4 / ... ) : 125 groups of M_=8 -> 32 blocks of 4 groups
    dim3 grid(32, 2, B_);
    hipLaunchKernelGGL(fsmn_kernel, grid, block, 0, stream, x, filt, out);
}

// Round 2
// 349.623 us; speedup vs baseline: 1.9288x; 1.9288x over previous
//
#include <hip/hip_runtime.h>

// FSMN depthwise strided FIR, parity-decomposed register-sliding implementation.
// B=32, T=2000, D=512, L_ORDER=R_ORDER=20, strides=2.
//
// out[b,2m  ,d] = sum_{i=0..20} fL[i]*xe[m-20+i] + sum_{j=0..19} fR[j]*xo[m+j]
// out[b,2m+1,d] = sum_{i=0..20} fL[i]*xo[m-20+i] + sum_{j=0..19} fR[j]*xe[m+1+j]
// where xe[s]=x[b,2s,d], xo[s]=x[b,2s+1,d], fL=filt[0..20], fR=filt[21..40].
//
// R2: M_=6 (was 8) + __launch_bounds__(256,1): round-1 spilled (VGPR snapped
// to 128 = data alone; 840 MB of scratch writes). 24 float4 data regs + addr
// now fits without spilling. Interior fast path drops all bounds checks.

#define B_ 32
#define T_ 2000
#define D_ 512
#define S_ 1000   // T/2 (downsampled length)
#define M_ 6      // m-positions per thread (=> 12 output rows per thread)

__device__ __forceinline__ float4 zf4() {
    float4 z; z.x = 0.f; z.y = 0.f; z.z = 0.f; z.w = 0.f; return z;
}

__device__ __forceinline__ void fma4(float4& a, const float4 f, const float4 w) {
    a.x = fmaf(f.x, w.x, a.x);
    a.y = fmaf(f.y, w.y, a.y);
    a.z = fmaf(f.z, w.z, a.z);
    a.w = fmaf(f.w, w.w, a.w);
}

template<bool CHK>
__device__ __forceinline__ void fsmn_body(const float* __restrict__ xb,
                                          const float* __restrict__ fb,
                                          float* __restrict__ ob, int m0)
{
    auto ldE = [&](int s) -> float4 {
        if (!CHK || (unsigned)s < (unsigned)S_)
            return *(const float4*)(xb + (size_t)(2 * s) * D_);
        return zf4();
    };
    auto ldO = [&](int s) -> float4 {
        if (!CHK || (unsigned)s < (unsigned)S_)
            return *(const float4*)(xb + (size_t)(2 * s + 1) * D_);
        return zf4();
    };

    float4 ae[M_], ao[M_];
#pragma unroll
    for (int m = 0; m < M_; ++m) { ae[m] = zf4(); ao[m] = zf4(); }

    float4 we[M_], wo[M_];

    // ---- Left passes (taps fL[0..20]) for both parities ----
#pragma unroll
    for (int m = 0; m < M_; ++m) {
        we[m] = ldE(m0 - 20 + m);
        wo[m] = ldO(m0 - 20 + m);
    }
#pragma unroll
    for (int i = 0; i < 21; ++i) {
        const float4 fv = *(const float4*)(fb + i * D_);
#pragma unroll
        for (int m = 0; m < M_; ++m) {
            fma4(ae[m], fv, we[m]);
            fma4(ao[m], fv, wo[m]);
        }
        if (i < 20) {
#pragma unroll
            for (int m = 0; m < M_ - 1; ++m) { we[m] = we[m + 1]; wo[m] = wo[m + 1]; }
            we[M_ - 1] = ldE(m0 - 20 + i + 1 + (M_ - 1));
            wo[M_ - 1] = ldO(m0 - 20 + i + 1 + (M_ - 1));
        }
    }

    // ---- Right passes (taps fR[0..19]) for both parities ----
#pragma unroll
    for (int m = 0; m < M_; ++m) {
        wo[m] = ldO(m0 + m);
        we[m] = ldE(m0 + 1 + m);
    }
#pragma unroll
    for (int j = 0; j < 20; ++j) {
        const float4 fv = *(const float4*)(fb + (21 + j) * D_);
#pragma unroll
        for (int m = 0; m < M_; ++m) {
            fma4(ae[m], fv, wo[m]);
            fma4(ao[m], fv, we[m]);
        }
        if (j < 19) {
#pragma unroll
            for (int m = 0; m < M_ - 1; ++m) { we[m] = we[m + 1]; wo[m] = wo[m + 1]; }
            wo[M_ - 1] = ldO(m0 + j + 1 + (M_ - 1));
            we[M_ - 1] = ldE(m0 + 1 + j + 1 + (M_ - 1));
        }
    }

    // ---- Store 2*M_ output rows (coalesced float4 across 64 lanes) ----
#pragma unroll
    for (int m = 0; m < M_; ++m) {
        if (!CHK || (m0 + m) < S_) {
            *(float4*)(ob + (size_t)(2 * (m0 + m))     * D_) = ae[m];
            *(float4*)(ob + (size_t)(2 * (m0 + m) + 1) * D_) = ao[m];
        }
    }
}

__global__ __launch_bounds__(256, 1) void fsmn_kernel(
    const float* __restrict__ x, const float* __restrict__ filt,
    float* __restrict__ out)
{
    const int d4 = threadIdx.x;            // 0..63 : float4 index within d-half
    const int mg = threadIdx.y;            // 0..3  : m-group within block (one wave each)
    const int mb = blockIdx.x;             // m-block
    const int dh = blockIdx.y;             // 0..1  : d-half
    const int b  = blockIdx.z;             // 0..31 : batch

    const int m0 = (mb * 4 + mg) * M_;     // base m for this thread
    if (m0 >= S_) return;                  // tail group slots

    const int d = (dh * 64 + d4) * 4;
    const float* xb = x + (size_t)b * T_ * D_ + d;
    const float* fb = filt + d;
    float*       ob = out + (size_t)b * T_ * D_ + d;

    // Interior iff every load index is in [0, S_): min = m0-20, max = m0+M_+19.
    const bool interior = (m0 >= 20) && (m0 <= S_ - M_ - 20);
    if (interior) fsmn_body<false>(xb, fb, ob, m0);
    else          fsmn_body<true >(xb, fb, ob, m0);
}

extern "C" void kernel_launch(void* const* d_in, const int* in_sizes, int n_in,
                              void* d_out, int out_size, void* d_ws, size_t ws_size,
                              hipStream_t stream) {
    const float* x    = (const float*)d_in[0];
    const float* filt = (const float*)d_in[1];
    float*       out  = (float*)d_out;

    dim3 block(64, 4, 1);
    // ceil(1000/6)=167 m-groups; 4 groups per block -> 42 blocks in x.
    dim3 grid(42, 2, B_);
    hipLaunchKernelGGL(fsmn_kernel, grid, block, 0, stream, x, filt, out);
}

// Round 3
// 340.154 us; speedup vs baseline: 1.9825x; 1.0278x over previous
//
#include <hip/hip_runtime.h>

// FSMN depthwise strided FIR, parity-decomposed register-sliding implementation.
// B=32, T=2000, D=512, L_ORDER=R_ORDER=20, strides=2.
//
// out[b,2m  ,d] = sum_{i=0..20} fL[i]*xe[m-20+i] + sum_{j=0..19} fR[j]*xo[m+j]
// out[b,2m+1,d] = sum_{i=0..20} fL[i]*xo[m-20+i] + sum_{j=0..19} fR[j]*xe[m+1+j]
// where xe[s]=x[b,2s,d], xo[s]=x[b,2s+1,d], fL=filt[0..20], fR=filt[21..40].
//
// R2 history: M_=8 + bounds(256,2) spilled (840 MB scratch writes, 530 us).
//             M_=6 + bounds(256,1) -> VGPR=256, occupancy 7%, latency-bound, 200 us.
// R3: M_=5 + bounds(256,2): 20 float4 data regs (80 VGPR) + temps < 128 cap
//     -> 4 waves/SIMD, no spill. Latency hiding via TLP instead of VGPR hoisting.

#define B_ 32
#define T_ 2000
#define D_ 512
#define S_ 1000   // T/2 (downsampled length)
#define M_ 5      // m-positions per thread (=> 10 output rows per thread)

__device__ __forceinline__ float4 zf4() {
    float4 z; z.x = 0.f; z.y = 0.f; z.z = 0.f; z.w = 0.f; return z;
}

__device__ __forceinline__ void fma4(float4& a, const float4 f, const float4 w) {
    a.x = fmaf(f.x, w.x, a.x);
    a.y = fmaf(f.y, w.y, a.y);
    a.z = fmaf(f.z, w.z, a.z);
    a.w = fmaf(f.w, w.w, a.w);
}

template<bool CHK>
__device__ __forceinline__ void fsmn_body(const float* __restrict__ xb,
                                          const float* __restrict__ fb,
                                          float* __restrict__ ob, int m0)
{
    auto ldE = [&](int s) -> float4 {
        if (!CHK || (unsigned)s < (unsigned)S_)
            return *(const float4*)(xb + (size_t)(2 * s) * D_);
        return zf4();
    };
    auto ldO = [&](int s) -> float4 {
        if (!CHK || (unsigned)s < (unsigned)S_)
            return *(const float4*)(xb + (size_t)(2 * s + 1) * D_);
        return zf4();
    };

    float4 ae[M_], ao[M_];
#pragma unroll
    for (int m = 0; m < M_; ++m) { ae[m] = zf4(); ao[m] = zf4(); }

    float4 we[M_], wo[M_];

    // ---- Left passes (taps fL[0..20]) for both parities ----
#pragma unroll
    for (int m = 0; m < M_; ++m) {
        we[m] = ldE(m0 - 20 + m);
        wo[m] = ldO(m0 - 20 + m);
    }
#pragma unroll
    for (int i = 0; i < 21; ++i) {
        const float4 fv = *(const float4*)(fb + i * D_);
#pragma unroll
        for (int m = 0; m < M_; ++m) {
            fma4(ae[m], fv, we[m]);
            fma4(ao[m], fv, wo[m]);
        }
        if (i < 20) {
#pragma unroll
            for (int m = 0; m < M_ - 1; ++m) { we[m] = we[m + 1]; wo[m] = wo[m + 1]; }
            we[M_ - 1] = ldE(m0 - 20 + i + 1 + (M_ - 1));
            wo[M_ - 1] = ldO(m0 - 20 + i + 1 + (M_ - 1));
        }
    }

    // ---- Right passes (taps fR[0..19]) for both parities ----
#pragma unroll
    for (int m = 0; m < M_; ++m) {
        wo[m] = ldO(m0 + m);
        we[m] = ldE(m0 + 1 + m);
    }
#pragma unroll
    for (int j = 0; j < 20; ++j) {
        const float4 fv = *(const float4*)(fb + (21 + j) * D_);
#pragma unroll
        for (int m = 0; m < M_; ++m) {
            fma4(ae[m], fv, wo[m]);
            fma4(ao[m], fv, we[m]);
        }
        if (j < 19) {
#pragma unroll
            for (int m = 0; m < M_ - 1; ++m) { we[m] = we[m + 1]; wo[m] = wo[m + 1]; }
            wo[M_ - 1] = ldO(m0 + j + 1 + (M_ - 1));
            we[M_ - 1] = ldE(m0 + 1 + j + 1 + (M_ - 1));
        }
    }

    // ---- Store 2*M_ output rows (coalesced float4 across 64 lanes) ----
#pragma unroll
    for (int m = 0; m < M_; ++m) {
        if (!CHK || (m0 + m) < S_) {
            *(float4*)(ob + (size_t)(2 * (m0 + m))     * D_) = ae[m];
            *(float4*)(ob + (size_t)(2 * (m0 + m) + 1) * D_) = ao[m];
        }
    }
}

__global__ __launch_bounds__(256, 2) void fsmn_kernel(
    const float* __restrict__ x, const float* __restrict__ filt,
    float* __restrict__ out)
{
    const int d4 = threadIdx.x;            // 0..63 : float4 index within d-half
    const int mg = threadIdx.y;            // 0..3  : m-group within block (one wave each)
    const int mb = blockIdx.x;             // m-block
    const int dh = blockIdx.y;             // 0..1  : d-half
    const int b  = blockIdx.z;             // 0..31 : batch

    const int m0 = (mb * 4 + mg) * M_;     // base m for this thread
    if (m0 >= S_) return;                  // tail group slots

    const int d = (dh * 64 + d4) * 4;
    const float* xb = x + (size_t)b * T_ * D_ + d;
    const float* fb = filt + d;
    float*       ob = out + (size_t)b * T_ * D_ + d;

    // Interior iff every load index is in [0, S_): min = m0-20, max = m0+M_+19.
    const bool interior = (m0 >= 20) && (m0 <= S_ - M_ - 20);
    if (interior) fsmn_body<false>(xb, fb, ob, m0);
    else          fsmn_body<true >(xb, fb, ob, m0);
}

extern "C" void kernel_launch(void* const* d_in, const int* in_sizes, int n_in,
                              void* d_out, int out_size, void* d_ws, size_t ws_size,
                              hipStream_t stream) {
    const float* x    = (const float*)d_in[0];
    const float* filt = (const float*)d_in[1];
    float*       out  = (float*)d_out;

    dim3 block(64, 4, 1);
    // ceil(1000/5)=200 m-groups; 4 groups per block -> 50 blocks in x.
    dim3 grid(50, 2, B_);
    hipLaunchKernelGGL(fsmn_kernel, grid, block, 0, stream, x, filt, out);
}